// Round 7
// baseline (358.770 us; speedup 1.0000x reference)
//
#include <hip/hip_runtime.h>
#include <math.h>
#include <stdint.h>

#define N_EMBED   2048
#define N_EXPERTS 64
#define TOP_K     8
#define NT        64            // tokens per block (main kernel)
#define KC        128           // k-chunk
#define NCH       (N_EMBED / KC)
#define XLD       65            // xs row pad (doubles)

// monotone map fp64 -> u64 (bigger value => bigger key), low 6 bits = tie-break
// by lane so lower expert index wins ties (matches lax.top_k)
__device__ __forceinline__ uint64_t mono_key(double v, int lane) {
    uint64_t u = (uint64_t)__double_as_longlong(v);
    u = (u >> 63) ? ~u : (u | 0x8000000000000000ULL);
    return (u & ~63ULL) | (uint64_t)(63 - lane);
}
__device__ __forceinline__ double key_val(uint64_t k) {
    uint64_t u = k & ~63ULL;
    u = (u >> 63) ? (u & 0x7FFFFFFFFFFFFFFFULL) : ~u;
    return __longlong_as_double((long long)u);
}

// ---- kernel A: combine W into fp64, layout Wg[eg][k][16] (eg = expert group) ----
__global__ void combine_w_kernel(const float* __restrict__ Wl,
                                 const float* __restrict__ Wn,
                                 double* __restrict__ Wg) {
    int f   = blockIdx.x * 256 + threadIdx.x;     // 0 .. 131071
    int e16 = f & 15;
    int k   = (f >> 4) & (N_EMBED - 1);
    int eg  = f >> 15;
    size_t src = (size_t)(eg * 16 + e16) * N_EMBED + k;
    Wg[f] = (double)Wl[src] + (double)Wn[src];
}

// ---- main kernel: lane = token, W via scalar loads (SGPR operand FMAs) ----
__global__ __launch_bounds__(256, 1)
void noisy_topk_main(const float* __restrict__ x, const double* __restrict__ Wg,
                     const float* __restrict__ bl, const float* __restrict__ bn,
                     float* __restrict__ out, int n_tokens) {
    __shared__ double xs[KC][XLD];     // 66,560 B; reused as nz[64][65] at the end

    const int tid  = threadIdx.x;
    const int lane = tid & 63;         // token within block
    const int wave = tid >> 6;         // expert group: experts [16*wave, 16*wave+16)
    const int t0   = blockIdx.x * NT;

    // wave-uniform W base -> scalar loads
    const int eg_u = __builtin_amdgcn_readfirstlane(wave);
    const double* wg = Wg + ((size_t)eg_u * N_EMBED * 16);

    // staging ownership: 4 threads per token, 32 consecutive k each
    const int stok = tid >> 2;
    const int sks  = (tid & 3) * 32;

    double acc[16];
#pragma unroll
    for (int e = 0; e < 16; ++e) acc[e] = 0.0;

    // prefetch chunk 0 (plain code, registers)
    float4 pf[8];
    {
        const float* xp = x + (size_t)(t0 + stok) * N_EMBED + sks;
#pragma unroll
        for (int j = 0; j < 8; ++j)
            pf[j] = *reinterpret_cast<const float4*>(xp + 4 * j);
    }

    for (int c = 0; c < NCH; ++c) {
        // commit prefetched regs -> LDS, transposed, fp64 (converted once here)
#pragma unroll
        for (int j = 0; j < 8; ++j) {
            xs[sks + 4 * j + 0][stok] = (double)pf[j].x;
            xs[sks + 4 * j + 1][stok] = (double)pf[j].y;
            xs[sks + 4 * j + 2][stok] = (double)pf[j].z;
            xs[sks + 4 * j + 3][stok] = (double)pf[j].w;
        }
        __syncthreads();

        // issue next chunk's global loads early (hidden under compute)
        if (c + 1 < NCH) {
            const float* xp = x + (size_t)(t0 + stok) * N_EMBED + (c + 1) * KC + sks;
#pragma unroll
            for (int j = 0; j < 8; ++j)
                pf[j] = *reinterpret_cast<const float4*>(xp + 4 * j);
        }

        // compute: per k, one per-lane ds_read_b64 (x) + 16 FMAs with SGPR W
        const double* wk = wg + (size_t)c * KC * 16;
#pragma unroll 4
        for (int kk = 0; kk < KC; ++kk) {
            const double xd = xs[kk][lane];
            const double* w = wk + (size_t)kk * 16;
#pragma unroll
            for (int e = 0; e < 16; ++e)
                acc[e] = fma(xd, w[e], acc[e]);
        }
        __syncthreads();
    }

    // logits into LDS, reusing xs as nz[token][expert]
#pragma unroll
    for (int e = 0; e < 16; ++e)
        xs[lane][wave * 16 + e] = acc[e];
    __syncthreads();

    // ---- wave-parallel top-8 + softmax + stores (proven rounds 2/4/6) ----
    const double myb = (double)bl[lane] + (double)bn[lane];   // lane = expert here
    float* out_router = out;
    float* out_idx    = out + (size_t)n_tokens * N_EXPERTS;
    const int tb = wave * 16;

    for (int t = 0; t < 16; ++t) {
        const double v = xs[tb + t][lane] + myb;
        uint64_t mykey = mono_key(v, lane);

        float pv[TOP_K]; int pi[TOP_K];
        double vtop0 = 0.0;
#pragma unroll
        for (int j = 0; j < TOP_K; ++j) {
            uint64_t k = mykey;
#pragma unroll
            for (int m = 32; m >= 1; m >>= 1) {
                uint64_t o = (uint64_t)__shfl_xor((unsigned long long)k, m);
                k = (o > k) ? o : k;
            }
            const int widx = 63 - (int)(k & 63);
            const double wv = key_val(k);
            if (j == 0) vtop0 = wv;
            pv[j] = __expf((float)(wv - vtop0));
            pi[j] = widx;
            if (lane == widx) mykey = 0;        // remove winner
        }
        float s = 0.f;
#pragma unroll
        for (int j = 0; j < TOP_K; ++j) s += pv[j];
        const float inv = 1.f / s;

        float r = 0.f;
#pragma unroll
        for (int j = 0; j < TOP_K; ++j) r = (lane == pi[j]) ? pv[j] * inv : r;
        out_router[(size_t)(t0 + tb + t) * N_EXPERTS + lane] = r;

        float iv = 0.f;
#pragma unroll
        for (int j = 0; j < TOP_K; ++j) iv = (lane == j) ? (float)pi[j] : iv;
        if (lane < TOP_K)
            out_idx[(size_t)(t0 + tb + t) * TOP_K + lane] = iv;
    }
}

// ---- fallback: proven round-6 kernel (used only if ws too small) ----
__global__ __launch_bounds__(512, 4)
void noisy_topk_fallback(const float* __restrict__ x,
                         const float* __restrict__ Wl, const float* __restrict__ bl,
                         const float* __restrict__ Wn, const float* __restrict__ bn,
                         float* __restrict__ out, int n_tokens) {
    __shared__ double Wt[64][N_EXPERTS];
    __shared__ double xsf[32][64];

    const int tid  = threadIdx.x;
    const int lane = tid & 63;
    const int wave = tid >> 6;
    const int t0   = blockIdx.x * 32;
    const int tb   = wave * 4;

    const int se = tid >> 3;
    const int sk = (tid & 7) * 8;
    const int st = tid >> 4;
    const int sx = (tid & 15) * 4;

    double acc[4];
#pragma unroll
    for (int t = 0; t < 4; ++t) acc[t] = 0.0;

    const double myb = (double)bl[lane] + (double)bn[lane];

    for (int c = 0; c < N_EMBED / 64; ++c) {
        const int kc = c * 64;
        __syncthreads();
        const float* wlp = Wl + (size_t)se * N_EMBED + kc + sk;
        const float* wnp = Wn + (size_t)se * N_EMBED + kc + sk;
#pragma unroll
        for (int i = 0; i < 2; ++i) {
            const float4 a = *reinterpret_cast<const float4*>(wlp + 4 * i);
            const float4 b = *reinterpret_cast<const float4*>(wnp + 4 * i);
            Wt[sk + 4 * i + 0][se] = (double)a.x + (double)b.x;
            Wt[sk + 4 * i + 1][se] = (double)a.y + (double)b.y;
            Wt[sk + 4 * i + 2][se] = (double)a.z + (double)b.z;
            Wt[sk + 4 * i + 3][se] = (double)a.w + (double)b.w;
        }
        {
            const float* xp = x + (size_t)(t0 + st) * N_EMBED + kc + sx;
            const float4 a = *reinterpret_cast<const float4*>(xp);
            xsf[st][sx + 0] = (double)a.x;
            xsf[st][sx + 1] = (double)a.y;
            xsf[st][sx + 2] = (double)a.z;
            xsf[st][sx + 3] = (double)a.w;
        }
        __syncthreads();
#pragma unroll 4
        for (int kk = 0; kk < 64; kk += 4) {
            const double w0 = Wt[kk + 0][lane];
            const double w1 = Wt[kk + 1][lane];
            const double w2 = Wt[kk + 2][lane];
            const double w3 = Wt[kk + 3][lane];
#pragma unroll
            for (int t = 0; t < 4; ++t) {
                const double2 p = *reinterpret_cast<const double2*>(&xsf[tb + t][kk]);
                const double2 q = *reinterpret_cast<const double2*>(&xsf[tb + t][kk + 2]);
                acc[t] = fma(p.x, w0, acc[t]);
                acc[t] = fma(p.y, w1, acc[t]);
                acc[t] = fma(q.x, w2, acc[t]);
                acc[t] = fma(q.y, w3, acc[t]);
            }
        }
    }

    float* out_router = out;
    float* out_idx    = out + (size_t)n_tokens * N_EXPERTS;
#pragma unroll
    for (int t = 0; t < 4; ++t) {
        const double v = acc[t] + myb;
        uint64_t mykey = mono_key(v, lane);
        float pv[TOP_K]; int pi[TOP_K];
        double vtop0 = 0.0;
#pragma unroll
        for (int j = 0; j < TOP_K; ++j) {
            uint64_t k = mykey;
#pragma unroll
            for (int m = 32; m >= 1; m >>= 1) {
                uint64_t o = (uint64_t)__shfl_xor((unsigned long long)k, m);
                k = (o > k) ? o : k;
            }
            const int widx = 63 - (int)(k & 63);
            const double wv = key_val(k);
            if (j == 0) vtop0 = wv;
            pv[j] = __expf((float)(wv - vtop0));
            pi[j] = widx;
            if (lane == widx) mykey = 0;
        }
        float s = 0.f;
#pragma unroll
        for (int j = 0; j < TOP_K; ++j) s += pv[j];
        const float inv = 1.f / s;
        float r = 0.f;
#pragma unroll
        for (int j = 0; j < TOP_K; ++j) r = (lane == pi[j]) ? pv[j] * inv : r;
        out_router[(size_t)(t0 + tb + t) * N_EXPERTS + lane] = r;
        float iv = 0.f;
#pragma unroll
        for (int j = 0; j < TOP_K; ++j) iv = (lane == j) ? (float)pi[j] : iv;
        if (lane < TOP_K)
            out_idx[(size_t)(t0 + tb + t) * TOP_K + lane] = iv;
    }
}

extern "C" void kernel_launch(void* const* d_in, const int* in_sizes, int n_in,
                              void* d_out, int out_size, void* d_ws, size_t ws_size,
                              hipStream_t stream) {
    const float* x  = (const float*)d_in[0];
    const float* Wl = (const float*)d_in[1];
    const float* bl = (const float*)d_in[2];
    const float* Wn = (const float*)d_in[3];
    const float* bn = (const float*)d_in[4];
    float* out = (float*)d_out;

    int n_tokens = in_sizes[0] / N_EMBED;              // 16384
    const size_t wg_bytes = (size_t)N_EXPERTS * N_EMBED * sizeof(double);  // 1 MB

    if (ws_size >= wg_bytes) {
        double* Wg = (double*)d_ws;
        hipLaunchKernelGGL(combine_w_kernel, dim3((N_EXPERTS * N_EMBED) / 256),
                           dim3(256), 0, stream, Wl, Wn, Wg);
        hipLaunchKernelGGL(noisy_topk_main, dim3(n_tokens / NT), dim3(256), 0, stream,
                           x, Wg, bl, bn, out, n_tokens);
    } else {
        hipLaunchKernelGGL(noisy_topk_fallback, dim3(n_tokens / 32), dim3(512), 0, stream,
                           x, Wl, bl, Wn, bn, out, n_tokens);
    }
}

// Round 8
// 190.234 us; speedup vs baseline: 1.8859x; 1.8859x over previous
//
#include <hip/hip_runtime.h>
#include <math.h>
#include <stdint.h>

#define N_EMBED   2048
#define N_EXPERTS 64
#define TOP_K     8
#define NT        64            // tokens per block
#define BLOCK     1024          // 16 waves
#define KC        128           // k-chunk
#define NCH       (N_EMBED / KC)

// monotone map fp64 -> u64 (bigger value => bigger key), low 6 bits = tie-break
// by lane so lower expert index wins ties (matches lax.top_k)
__device__ __forceinline__ uint64_t mono_key(double v, int lane) {
    uint64_t u = (uint64_t)__double_as_longlong(v);
    u = (u >> 63) ? ~u : (u | 0x8000000000000000ULL);
    return (u & ~63ULL) | (uint64_t)(63 - lane);
}
__device__ __forceinline__ double key_val(uint64_t k) {
    uint64_t u = k & ~63ULL;
    u = (u >> 63) ? (u & 0x7FFFFFFFFFFFFFFFULL) : ~u;
    return __longlong_as_double((long long)u);
}

// ---- kernel A: combine W into fp64, layout Wg[eg][k][8] (eg = expert/8) ----
__global__ void combine_w_kernel(const float* __restrict__ Wl,
                                 const float* __restrict__ Wn,
                                 double* __restrict__ Wg) {
    int f  = blockIdx.x * 256 + threadIdx.x;      // 0 .. 131071
    int e8 = f & 7;
    int k  = (f >> 3) & (N_EMBED - 1);
    int eg = f >> 14;
    size_t src = (size_t)(eg * 8 + e8) * N_EMBED + k;
    Wg[f] = (double)Wl[src] + (double)Wn[src];
}

// ---- main: lane=token, 16 waves = 8 expert-groups x 2 K-halves ----
__global__ __launch_bounds__(BLOCK, 1)
void noisy_topk_main(const float* __restrict__ x, const double* __restrict__ Wg,
                     const float* __restrict__ bl, const float* __restrict__ bn,
                     float* __restrict__ out, int n_tokens) {
    __shared__ double xs[NT][130];     // 66,560 B; reused for partials+logits

    const int tid  = threadIdx.x;
    const int lane = tid & 63;         // token within block (compute phase)
    const int wave = tid >> 6;         // 0..15
    const int t0   = blockIdx.x * NT;

    const int wid_u = __builtin_amdgcn_readfirstlane(wave);
    const int eg    = wid_u & 7;       // expert group: experts [8eg, 8eg+8)
    const int h     = wid_u >> 3;      // K-half within each chunk

    // staging ownership: 16 threads per token, 8 consecutive k each
    const int stok = tid >> 4;
    const int sks  = (tid & 15) * 8;

    double acc[8];
#pragma unroll
    for (int e = 0; e < 8; ++e) acc[e] = 0.0;

    // prefetch chunk 0
    float4 pf0, pf1;
    {
        const float* xp = x + (size_t)(t0 + stok) * N_EMBED + sks;
        pf0 = *reinterpret_cast<const float4*>(xp);
        pf1 = *reinterpret_cast<const float4*>(xp + 4);
    }

    for (int c = 0; c < NCH; ++c) {
        // commit prefetched regs -> LDS (fp32->fp64 once), xs[token][k]
        {
            double2 d0, d1, d2, d3;
            d0.x = (double)pf0.x; d0.y = (double)pf0.y;
            d1.x = (double)pf0.z; d1.y = (double)pf0.w;
            d2.x = (double)pf1.x; d2.y = (double)pf1.y;
            d3.x = (double)pf1.z; d3.y = (double)pf1.w;
            *reinterpret_cast<double2*>(&xs[stok][sks + 0]) = d0;
            *reinterpret_cast<double2*>(&xs[stok][sks + 2]) = d1;
            *reinterpret_cast<double2*>(&xs[stok][sks + 4]) = d2;
            *reinterpret_cast<double2*>(&xs[stok][sks + 6]) = d3;
        }
        __syncthreads();

        // issue next chunk's global loads early (hidden under compute)
        if (c + 1 < NCH) {
            const float* xp = x + (size_t)(t0 + stok) * N_EMBED + (c + 1) * KC + sks;
            pf0 = *reinterpret_cast<const float4*>(xp);
            pf1 = *reinterpret_cast<const float4*>(xp + 4);
        }

        // compute: per 2k: 1 ds_read_b128 (x) + 2 s_load_dwordx16 (W) + 16 FMA
        const double* wk = Wg + ((size_t)eg * N_EMBED + (size_t)c * KC + h * 64) * 8;
        const double* xr = &xs[lane][h * 64];
#pragma unroll 2
        for (int i = 0; i < 32; ++i) {
            const double2 x2 = *reinterpret_cast<const double2*>(xr + 2 * i);
            const double* w = wk + 16 * i;
#pragma unroll
            for (int e = 0; e < 8; ++e) acc[e] = fma(x2.x, w[e], acc[e]);
#pragma unroll
            for (int e = 0; e < 8; ++e) acc[e] = fma(x2.y, w[8 + e], acc[e]);
        }
        __syncthreads();
    }

    // ---- combine K-halves, add bias, build logits nz[token][expert] ----
    double* flat = &xs[0][0];
    double* part = flat;               // part[eg][lane][8]  : 4096 doubles
    double* nz   = flat + 4096;        // nz[t*65 + e]       : 4160 doubles

    if (h == 1) {
#pragma unroll
        for (int e = 0; e < 8; ++e)
            part[eg * 512 + lane * 8 + e] = acc[e];
    }
    __syncthreads();
    if (h == 0) {
#pragma unroll
        for (int e = 0; e < 8; ++e) {
            const int ex = eg * 8 + e;
            const double be = (double)bl[ex] + (double)bn[ex];
            nz[lane * 65 + ex] = acc[e] + part[eg * 512 + lane * 8 + e] + be;
        }
    }
    __syncthreads();

    // ---- wave-parallel top-8 + softmax + stores (proven rounds 2/4/6) ----
    float* out_router = out;
    float* out_idx    = out + (size_t)n_tokens * N_EXPERTS;
    const int tb = wave * 4;           // 16 waves x 4 tokens

#pragma unroll
    for (int t = 0; t < 4; ++t) {
        const double v = nz[(tb + t) * 65 + lane];   // lane = expert here
        uint64_t mykey = mono_key(v, lane);

        float pv[TOP_K]; int pi[TOP_K];
        double vtop0 = 0.0;
#pragma unroll
        for (int j = 0; j < TOP_K; ++j) {
            uint64_t k = mykey;
#pragma unroll
            for (int m = 32; m >= 1; m >>= 1) {
                uint64_t o = (uint64_t)__shfl_xor((unsigned long long)k, m);
                k = (o > k) ? o : k;
            }
            const int widx = 63 - (int)(k & 63);
            const double wv = key_val(k);
            if (j == 0) vtop0 = wv;
            pv[j] = __expf((float)(wv - vtop0));
            pi[j] = widx;
            if (lane == widx) mykey = 0;        // remove winner
        }
        float s = 0.f;
#pragma unroll
        for (int j = 0; j < TOP_K; ++j) s += pv[j];
        const float inv = 1.f / s;

        float r = 0.f;
#pragma unroll
        for (int j = 0; j < TOP_K; ++j) r = (lane == pi[j]) ? pv[j] * inv : r;
        out_router[(size_t)(t0 + tb + t) * N_EXPERTS + lane] = r;

        float iv = 0.f;
#pragma unroll
        for (int j = 0; j < TOP_K; ++j) iv = (lane == j) ? (float)pi[j] : iv;
        if (lane < TOP_K)
            out_idx[(size_t)(t0 + tb + t) * TOP_K + lane] = iv;
    }
}

// ---- fallback: proven round-6 kernel (used only if ws too small) ----
__global__ __launch_bounds__(512, 4)
void noisy_topk_fallback(const float* __restrict__ x,
                         const float* __restrict__ Wl, const float* __restrict__ bl,
                         const float* __restrict__ Wn, const float* __restrict__ bn,
                         float* __restrict__ out, int n_tokens) {
    __shared__ double Wt[64][N_EXPERTS];
    __shared__ double xsf[32][64];

    const int tid  = threadIdx.x;
    const int lane = tid & 63;
    const int wave = tid >> 6;
    const int t0   = blockIdx.x * 32;
    const int tb   = wave * 4;

    const int se = tid >> 3;
    const int sk = (tid & 7) * 8;
    const int st = tid >> 4;
    const int sx = (tid & 15) * 4;

    double acc[4];
#pragma unroll
    for (int t = 0; t < 4; ++t) acc[t] = 0.0;

    const double myb = (double)bl[lane] + (double)bn[lane];

    for (int c = 0; c < N_EMBED / 64; ++c) {
        const int kc = c * 64;
        __syncthreads();
        const float* wlp = Wl + (size_t)se * N_EMBED + kc + sk;
        const float* wnp = Wn + (size_t)se * N_EMBED + kc + sk;
#pragma unroll
        for (int i = 0; i < 2; ++i) {
            const float4 a = *reinterpret_cast<const float4*>(wlp + 4 * i);
            const float4 b = *reinterpret_cast<const float4*>(wnp + 4 * i);
            Wt[sk + 4 * i + 0][se] = (double)a.x + (double)b.x;
            Wt[sk + 4 * i + 1][se] = (double)a.y + (double)b.y;
            Wt[sk + 4 * i + 2][se] = (double)a.z + (double)b.z;
            Wt[sk + 4 * i + 3][se] = (double)a.w + (double)b.w;
        }
        {
            const float* xp = x + (size_t)(t0 + st) * N_EMBED + kc + sx;
            const float4 a = *reinterpret_cast<const float4*>(xp);
            xsf[st][sx + 0] = (double)a.x;
            xsf[st][sx + 1] = (double)a.y;
            xsf[st][sx + 2] = (double)a.z;
            xsf[st][sx + 3] = (double)a.w;
        }
        __syncthreads();
#pragma unroll 4
        for (int kk = 0; kk < 64; kk += 4) {
            const double w0 = Wt[kk + 0][lane];
            const double w1 = Wt[kk + 1][lane];
            const double w2 = Wt[kk + 2][lane];
            const double w3 = Wt[kk + 3][lane];
#pragma unroll
            for (int t = 0; t < 4; ++t) {
                const double2 p = *reinterpret_cast<const double2*>(&xsf[tb + t][kk]);
                const double2 q = *reinterpret_cast<const double2*>(&xsf[tb + t][kk + 2]);
                acc[t] = fma(p.x, w0, acc[t]);
                acc[t] = fma(p.y, w1, acc[t]);
                acc[t] = fma(q.x, w2, acc[t]);
                acc[t] = fma(q.y, w3, acc[t]);
            }
        }
    }

    float* out_router = out;
    float* out_idx    = out + (size_t)n_tokens * N_EXPERTS;
#pragma unroll
    for (int t = 0; t < 4; ++t) {
        const double v = acc[t] + myb;
        uint64_t mykey = mono_key(v, lane);
        float pv[TOP_K]; int pi[TOP_K];
        double vtop0 = 0.0;
#pragma unroll
        for (int j = 0; j < TOP_K; ++j) {
            uint64_t k = mykey;
#pragma unroll
            for (int m = 32; m >= 1; m >>= 1) {
                uint64_t o = (uint64_t)__shfl_xor((unsigned long long)k, m);
                k = (o > k) ? o : k;
            }
            const int widx = 63 - (int)(k & 63);
            const double wv = key_val(k);
            if (j == 0) vtop0 = wv;
            pv[j] = __expf((float)(wv - vtop0));
            pi[j] = widx;
            if (lane == widx) mykey = 0;
        }
        float s = 0.f;
#pragma unroll
        for (int j = 0; j < TOP_K; ++j) s += pv[j];
        const float inv = 1.f / s;
        float r = 0.f;
#pragma unroll
        for (int j = 0; j < TOP_K; ++j) r = (lane == pi[j]) ? pv[j] * inv : r;
        out_router[(size_t)(t0 + tb + t) * N_EXPERTS + lane] = r;
        float iv = 0.f;
#pragma unroll
        for (int j = 0; j < TOP_K; ++j) iv = (lane == j) ? (float)pi[j] : iv;
        if (lane < TOP_K)
            out_idx[(size_t)(t0 + tb + t) * TOP_K + lane] = iv;
    }
}

extern "C" void kernel_launch(void* const* d_in, const int* in_sizes, int n_in,
                              void* d_out, int out_size, void* d_ws, size_t ws_size,
                              hipStream_t stream) {
    const float* x  = (const float*)d_in[0];
    const float* Wl = (const float*)d_in[1];
    const float* bl = (const float*)d_in[2];
    const float* Wn = (const float*)d_in[3];
    const float* bn = (const float*)d_in[4];
    float* out = (float*)d_out;

    int n_tokens = in_sizes[0] / N_EMBED;              // 16384
    const size_t wg_bytes = (size_t)N_EXPERTS * N_EMBED * sizeof(double);  // 1 MB

    if (ws_size >= wg_bytes) {
        double* Wg = (double*)d_ws;
        hipLaunchKernelGGL(combine_w_kernel, dim3((N_EXPERTS * N_EMBED) / 256),
                           dim3(256), 0, stream, Wl, Wn, Wg);
        hipLaunchKernelGGL(noisy_topk_main, dim3(n_tokens / NT), dim3(BLOCK), 0, stream,
                           x, Wg, bl, bn, out, n_tokens);
    } else {
        hipLaunchKernelGGL(noisy_topk_fallback, dim3(n_tokens / 32), dim3(512), 0, stream,
                           x, Wl, bl, Wn, bn, out, n_tokens);
    }
}